// Round 1
// baseline (323.634 us; speedup 1.0000x reference)
//
#include <hip/hip_runtime.h>

// Problem constants (match reference)
#define NUM_P      16
#define STEP       4
#define NUM_BLOCKS 256   // blocks per permutation (DIM / STEP)
#define DIM        1024
#define BATCH      4096

// Kernel A: extract the block permutation from the dense T matrices.
// T[p, 4r, 4c] == 1.0 exactly when permutation p maps block-row r to
// block-col c. The eye-block's first-row 1 sits at column 4c, i.e. lane 0
// of the 16B-aligned float4 starting at T[p][4r][4c]. Reading float4
// makes consecutive c-threads read consecutive 16B — fully coalesced
// (the old version read 4B at 64B stride: 1 lane per cache line).
__global__ __launch_bounds__(256) void extract_perm_kernel(
    const float4* __restrict__ T4, int* __restrict__ perm) {
    int idx = blockIdx.x * blockDim.x + threadIdx.x;  // p*65536 + r*256 + c
    int c = idx & (NUM_BLOCKS - 1);
    int r = (idx >> 8) & (NUM_BLOCKS - 1);
    int p = idx >> 16;
    // float4 index of T[p][4r][4c]
    size_t off4 = (size_t)p * (DIM * DIM / 4) + (size_t)(STEP * r) * (DIM / 4) + c;
    float4 v = T4[off4];
    if (v.x != 0.0f) {
        perm[p * NUM_BLOCKS + r] = c;
    }
}

// Kernel B: one block per batch row b. Stage the 4 KB row of x in LDS
// ONCE, then emit all 16 permuted copies as coalesced 4 KB stores.
// This removes the 16x re-read of x through L3/HBM (x = 16 MiB doesn't
// fit a 4 MiB per-XCD L2; the old per-(i,b) blocks gathered 16B granules
// straight from L3 with ~4-8x line-granularity amplification).
// The random access now lives in LDS where it is cheap.
__global__ __launch_bounds__(256) void gather_kernel(
    const float4* __restrict__ x4,
    const int* __restrict__ perm,
    const int* __restrict__ indices,
    float4* __restrict__ out4) {
    __shared__ float4 row[NUM_BLOCKS];        // 4 KB: x row b
    __shared__ int cperm[NUM_P][NUM_BLOCKS];  // 16 KB: perms in output order
    const int tid = threadIdx.x;
    const int b = blockIdx.x;

    // Coalesced load of row b (64B/wave-lane-group, 4 KB total).
    row[tid] = x4[(size_t)b * NUM_BLOCKS + tid];

    // Stage the 16 permutations, already reordered by indices[].
    // indices/perm are 64B/16KB resident in L2 — these hit every time.
#pragma unroll
    for (int i = 0; i < NUM_P; ++i) {
        int q = indices[i];                   // wave-uniform broadcast
        cperm[i][tid] = perm[q * NUM_BLOCKS + tid];
    }
    __syncthreads();

    // 16 coalesced 4 KB stores; gather happens in LDS.
#pragma unroll
    for (int i = 0; i < NUM_P; ++i) {
        int c = cperm[i][tid];
        out4[((size_t)i * BATCH + b) * NUM_BLOCKS + tid] = row[c];
    }
}

extern "C" void kernel_launch(void* const* d_in, const int* in_sizes, int n_in,
                              void* d_out, int out_size, void* d_ws, size_t ws_size,
                              hipStream_t stream) {
    const float* x       = (const float*)d_in[0];   // [BATCH, DIM] fp32
    const float* T       = (const float*)d_in[1];   // [NUM_P, DIM, DIM] fp32
    const int*   indices = (const int*)d_in[2];     // [NUM_P] int32
    float* out = (float*)d_out;                     // [NUM_P*BATCH, DIM] fp32

    int* perm = (int*)d_ws;                         // NUM_P * NUM_BLOCKS ints (16 KiB)

    // Kernel A: 16*256*256 = 1,048,576 threads, coalesced float4 reads (16 MiB).
    {
        int total = NUM_P * NUM_BLOCKS * NUM_BLOCKS;
        dim3 block(256);
        dim3 grid(total / 256);
        extract_perm_kernel<<<grid, block, 0, stream>>>((const float4*)T, perm);
    }

    // Kernel B: one block per batch row; 4096 blocks x 256 threads.
    // LDS 20 KB/block -> 8 blocks/CU (32 waves/CU, full occupancy).
    {
        dim3 block(256);
        dim3 grid(BATCH);
        gather_kernel<<<grid, block, 0, stream>>>(
            (const float4*)x, perm, indices, (float4*)out);
    }
    (void)in_sizes; (void)n_in; (void)out_size; (void)ws_size;
}